// Round 3
// baseline (574.548 us; speedup 1.0000x reference)
//
#include <hip/hip_runtime.h>
#include <hip/hip_bf16.h>
#include <math.h>

#define B_ 64
#define T_ 4096
#define C_ 256
#define H_ 4
#define HD_ 64
#define EPS_ 1e-5f

typedef __attribute__((ext_vector_type(4))) float floatx4;
typedef __attribute__((ext_vector_type(8))) short short8;   // 8 bf16 = 4 VGPRs (MFMA A/B frag)

#if __has_builtin(__builtin_amdgcn_cvt_pk_bf16_f32)
typedef __attribute__((ext_vector_type(2))) __bf16 bf16x2_t;
__device__ __forceinline__ unsigned int pack_bf16x2(float a, float b) {
    bf16x2_t v = __builtin_amdgcn_cvt_pk_bf16_f32(a, b);
    return __builtin_bit_cast(unsigned int, v);
}
#else
__device__ __forceinline__ unsigned int pack_bf16x2(float a, float b) {
    unsigned int ua = __builtin_bit_cast(unsigned int, a);
    unsigned int ub = __builtin_bit_cast(unsigned int, b);
    ua = (ua + 0x7fffu + ((ua >> 16) & 1u)) >> 16;   // RNE
    ub = (ub + 0x7fffu + ((ub >> 16) & 1u)) >> 16;
    return ua | (ub << 16);
}
#endif

// tanh(x) = sign(x) * (1 - e) / (1 + e), e = exp(-2|x|)  (~7 VALU instrs vs ~30 for tanhf)
__device__ __forceinline__ float fast_tanh(float v) {
    float a = fabsf(v);
    float e = __expf(-2.0f * a);
    float r = (1.0f - e) / (1.0f + e);
    return copysignf(r, v);
}

// ---------------- K0: W1 (H,C,HD) fp32 -> W1T[n][c] bf16, n = h*64+d ----------------
__global__ void k0_w1t(const float* __restrict__ W1, unsigned short* __restrict__ w1t) {
    int n = blockIdx.x;     // 256
    int c = threadIdx.x;    // 256
    int h = n >> 6, d = n & 63;
    float v = W1[(h * C_ + c) * HD_ + d];
    unsigned int u = __builtin_bit_cast(unsigned int, v);
    u = (u + 0x7fffu + ((u >> 16) & 1u)) >> 16;
    w1t[n * C_ + c] = (unsigned short)u;
}

// ---------------- K1 fused: scores (MFMA, no LDS staging) + partial softmax + partial context --------
// grid 4096 (64 rows each), block 256 = 4 waves, wave w = head w.
// A frags loaded straight from x (fp32->bf16 in-register); B frags straight from w1t (L1-hot).
// No K-loop barriers; single __syncthreads before phase 3.
__global__ __launch_bounds__(256, 3)
void k1_fused(const float* __restrict__ x, const unsigned short* __restrict__ w1t,
              const float* __restrict__ b1, const float* __restrict__ w2,
              float* __restrict__ rawscore, float* __restrict__ ctxp,
              float* __restrict__ mS) {
    __shared__ float sS[4 * 64];                   // raw scores per head
    __shared__ __align__(16) float sP4[64 * 4];    // exp(s - m_loc), layout [t][h]

    const int tid  = threadIdx.x;
    const int lane = tid & 63;
    const int w    = tid >> 6;        // wave id == head id
    const int nl   = lane & 15;
    const int q    = lane >> 4;
    const int rowbase = blockIdx.x * 64;       // row = b*T + t
    const int b       = blockIdx.x >> 6;       // 64 blocks per batch
    const int tbase   = (blockIdx.x & 63) * 64;

    floatx4 acc[4][4];
    #pragma unroll
    for (int i = 0; i < 4; ++i)
        #pragma unroll
        for (int j = 0; j < 4; ++j)
            acc[i][j] = (floatx4){0.f, 0.f, 0.f, 0.f};

    // A-frag for 16x16x32: lane(nl,q) needs x[row = mtile + nl][k = ks*32 + q*8 .. +7]
    const float* aBase = x + (long)(rowbase + nl) * C_ + q * 8;
    // B-frag: lane(nl,q) needs w1t[n = w*64 + nb*16 + nl][k = ks*32 + q*8 .. +7] (16B contiguous)
    const unsigned short* bBase = w1t + (long)(w * 64 + nl) * C_ + q * 8;

    for (int ks = 0; ks < 8; ++ks) {
        const int kb = ks * 32;
        uint4 bF[4];
        #pragma unroll
        for (int nb = 0; nb < 4; ++nb)
            bF[nb] = *(const uint4*)(bBase + nb * 16 * C_ + kb);
        #pragma unroll
        for (int mb = 0; mb < 4; ++mb) {
            const float4* ap = (const float4*)(aBase + (long)mb * 16 * C_ + kb);
            float4 f0 = ap[0], f1 = ap[1];
            uint4 ua;
            ua.x = pack_bf16x2(f0.x, f0.y);
            ua.y = pack_bf16x2(f0.z, f0.w);
            ua.z = pack_bf16x2(f1.x, f1.y);
            ua.w = pack_bf16x2(f1.z, f1.w);
            short8 aF = __builtin_bit_cast(short8, ua);
            #pragma unroll
            for (int nb = 0; nb < 4; ++nb)
                acc[mb][nb] = __builtin_amdgcn_mfma_f32_16x16x32_bf16(
                    aF, __builtin_bit_cast(short8, bF[nb]), acc[mb][nb], 0, 0, 0);
        }
    }

    // epilogue: s(t) = sum_d tanh(P + b1)*w2  (d = nb*16 + nl, t = mb*16 + q*4 + r)
    float b1v[4], w2v[4];
    #pragma unroll
    for (int nb = 0; nb < 4; ++nb) {
        int d = nb * 16 + nl;
        b1v[nb] = b1[w * HD_ + d];
        w2v[nb] = w2[w * HD_ + d];
    }
    #pragma unroll
    for (int mb = 0; mb < 4; ++mb) {
        float p[4];
        #pragma unroll
        for (int r = 0; r < 4; ++r) {
            float s = 0.f;
            #pragma unroll
            for (int nb = 0; nb < 4; ++nb)
                s += fast_tanh(acc[mb][nb][r] + b1v[nb]) * w2v[nb];
            p[r] = s;
        }
        #pragma unroll
        for (int m = 1; m < 16; m <<= 1)
            #pragma unroll
            for (int r = 0; r < 4; ++r)
                p[r] += __shfl_xor(p[r], m, 64);
        if (nl == 0) {
            #pragma unroll
            for (int r = 0; r < 4; ++r)
                sS[w * 64 + mb * 16 + q * 4 + r] = p[r];
        }
    }

    // phase 2: per-head local softmax partials over this block's 64 t values
    {
        float s = sS[w * 64 + lane];
        float m = s;
        #pragma unroll
        for (int off = 1; off < 64; off <<= 1)
            m = fmaxf(m, __shfl_xor(m, off, 64));
        float e = __expf(s - m);
        float Ss = e;
        #pragma unroll
        for (int off = 1; off < 64; off <<= 1)
            Ss += __shfl_xor(Ss, off, 64);
        sP4[lane * 4 + w] = e;                     // [t][h] for vectorized phase-3 read
        rawscore[((long)(b * H_ + w)) * T_ + tbase + lane] = s;
        if (lane == 0) {
            mS[((long)blockIdx.x * H_ + w) * 2 + 0] = m;
            mS[((long)blockIdx.x * H_ + w) * 2 + 1] = Ss;
        }
    }
    __syncthreads();

    // phase 3: partial contexts ctx_loc[h][c] = sum_t p[t][h] * x[t][c]  (x re-read, L1/L2-hot)
    {
        float c0 = 0.f, c1 = 0.f, c2 = 0.f, c3 = 0.f;
        const float* xr = x + (long)rowbase * C_ + tid;
        const float4* pv4 = (const float4*)sP4;
        #pragma unroll 8
        for (int t = 0; t < 64; ++t) {
            float xv = xr[(long)t * C_];
            float4 pv = pv4[t];                    // one broadcast ds_read_b128
            c0 += pv.x * xv;
            c1 += pv.y * xv;
            c2 += pv.z * xv;
            c3 += pv.w * xv;
        }
        float* o = ctxp + (long)blockIdx.x * (H_ * C_) + tid;
        o[0]   = c0;
        o[256] = c1;
        o[512] = c2;
        o[768] = c3;
    }
}

// ---------------- K2: combine partials -> weights (in-place over raw scores) + multi ----------------
__global__ void k2_combine(const float* __restrict__ ctxp, const float* __restrict__ mS,
                           float* __restrict__ weights, float* __restrict__ multi) {
    __shared__ float sm[64], sSl[64], sc[64];
    int bh = blockIdx.x;              // b*H + h
    int b = bh >> 2, h = bh & 3;
    int tid = threadIdx.x;
    if (tid < 64) {
        long blk = (long)b * 64 + tid;
        sm[tid]  = mS[(blk * H_ + h) * 2 + 0];
        sSl[tid] = mS[(blk * H_ + h) * 2 + 1];
    }
    __syncthreads();
    float m = -INFINITY;
    #pragma unroll 8
    for (int j = 0; j < 64; ++j) m = fmaxf(m, sm[j]);
    if (tid < 64) sc[tid] = __expf(sm[tid] - m);
    __syncthreads();
    float S = 0.f;
    #pragma unroll 8
    for (int j = 0; j < 64; ++j) S += sSl[j] * sc[j];
    float invS = 1.0f / S;

    float acc = 0.f;
    #pragma unroll 4
    for (int j = 0; j < 64; ++j)
        acc += ctxp[((long)(b * 64 + j) * H_ + h) * C_ + tid] * sc[j];
    multi[(long)b * (H_ * C_) + h * C_ + tid] = acc * invS;

    float* wr = weights + (long)bh * T_;
    #pragma unroll
    for (int i = 0; i < 16; ++i) {
        int t = tid + i * 256;
        float sv = wr[t];                 // raw score written by k1_fused
        wr[t] = __expf(sv - m) * invS;
    }
}

// ---------------- K4: Wo projection + bias + LayerNorm ----------------
__global__ void k4_out(const float* __restrict__ multiG, const float* __restrict__ Wo,
                       const float* __restrict__ bo, const float* __restrict__ gamma,
                       const float* __restrict__ beta, float* __restrict__ out) {
    __shared__ float multi[1024];
    __shared__ float red[256];
    int b = blockIdx.x, tid = threadIdx.x;
    {
        const float4* src = (const float4*)(multiG + (long)b * 1024);
        float4* dst = (float4*)multi;
        if (tid < 256) dst[tid] = src[tid];   // 256 float4 = 1024 floats
    }
    __syncthreads();
    float a0 = 0.f, a1 = 0.f, a2 = 0.f, a3 = 0.f;
    const float4* wrow = (const float4*)(Wo + (long)tid * 1024);
    const float4* mv = (const float4*)multi;
    #pragma unroll 8
    for (int j4 = 0; j4 < 256; j4 += 4) {
        float4 w0 = wrow[j4],     m0 = mv[j4];
        float4 w1 = wrow[j4 + 1], m1 = mv[j4 + 1];
        float4 w2 = wrow[j4 + 2], m2 = mv[j4 + 2];
        float4 w3 = wrow[j4 + 3], m3 = mv[j4 + 3];
        a0 += m0.x * w0.x + m0.y * w0.y + m0.z * w0.z + m0.w * w0.w;
        a1 += m1.x * w1.x + m1.y * w1.y + m1.z * w1.z + m1.w * w1.w;
        a2 += m2.x * w2.x + m2.y * w2.y + m2.z * w2.z + m2.w * w2.w;
        a3 += m3.x * w3.x + m3.y * w3.y + m3.z * w3.z + m3.w * w3.w;
    }
    float acc = bo[tid] + ((a0 + a1) + (a2 + a3));
    red[tid] = acc; __syncthreads();
    for (int st = 128; st > 0; st >>= 1) {
        if (tid < st) red[tid] += red[tid + st];
        __syncthreads();
    }
    float mu = red[0] * (1.0f / 256.0f); __syncthreads();
    float dv = acc - mu;
    red[tid] = dv * dv; __syncthreads();
    for (int st = 128; st > 0; st >>= 1) {
        if (tid < st) red[tid] += red[tid + st];
        __syncthreads();
    }
    float var = red[0] * (1.0f / 256.0f);
    out[(long)b * C_ + tid] = dv * rsqrtf(var + EPS_) * gamma[tid] + beta[tid];
}

extern "C" void kernel_launch(void* const* d_in, const int* in_sizes, int n_in,
                              void* d_out, int out_size, void* d_ws, size_t ws_size,
                              hipStream_t stream) {
    const float* x     = (const float*)d_in[0];
    const float* W1    = (const float*)d_in[1];
    const float* b1    = (const float*)d_in[2];
    const float* w2    = (const float*)d_in[3];
    const float* Wo    = (const float*)d_in[4];
    const float* bo    = (const float*)d_in[5];
    const float* gamma = (const float*)d_in[6];
    const float* beta  = (const float*)d_in[7];

    float* out     = (float*)d_out;          // (B,C) = 16384 floats
    float* weights = out + B_ * C_;          // (B,H,T) = 1048576 floats (holds raw scores first)

    // workspace: ctxp 4096*4*256 fp32 (16 MiB) + mS 4096*4*2 + multi 64*1024 + w1t
    float* ctxp  = (float*)d_ws;
    float* mS    = ctxp + (long)4096 * H_ * C_;
    float* multi = mS + (long)4096 * H_ * 2;
    unsigned short* w1t = (unsigned short*)(multi + B_ * H_ * C_);

    k0_w1t    <<<256, 256, 0, stream>>>(W1, w1t);
    k1_fused  <<<4096, 256, 0, stream>>>(x, w1t, b1, w2, weights, ctxp, mS);
    k2_combine<<<256, 256, 0, stream>>>(ctxp, mS, weights, multi);
    k4_out    <<<64, 256, 0, stream>>>(multi, Wo, bo, gamma, beta, out);
}

// Round 4
// 485.611 us; speedup vs baseline: 1.1831x; 1.1831x over previous
//
#include <hip/hip_runtime.h>
#include <hip/hip_bf16.h>
#include <math.h>

#define B_ 64
#define T_ 4096
#define C_ 256
#define H_ 4
#define HD_ 64
#define EPS_ 1e-5f

typedef __attribute__((ext_vector_type(4))) float floatx4;
typedef __attribute__((ext_vector_type(8))) short short8;   // 8 bf16 = 4 VGPRs (MFMA A/B frag)

#if __has_builtin(__builtin_amdgcn_cvt_pk_bf16_f32)
typedef __attribute__((ext_vector_type(2))) __bf16 bf16x2_t;
__device__ __forceinline__ unsigned int pack_bf16x2(float a, float b) {
    bf16x2_t v = __builtin_amdgcn_cvt_pk_bf16_f32(a, b);
    return __builtin_bit_cast(unsigned int, v);
}
#else
__device__ __forceinline__ unsigned int pack_bf16x2(float a, float b) {
    unsigned int ua = __builtin_bit_cast(unsigned int, a);
    unsigned int ub = __builtin_bit_cast(unsigned int, b);
    ua = (ua + 0x7fffu + ((ua >> 16) & 1u)) >> 16;   // RNE
    ub = (ub + 0x7fffu + ((ub >> 16) & 1u)) >> 16;
    return ua | (ub << 16);
}
#endif

// tanh(x) = sign(x) * (1 - e) / (1 + e), e = exp(-2|x|)  (~7 VALU instrs vs ~30 for tanhf)
__device__ __forceinline__ float fast_tanh(float v) {
    float a = fabsf(v);
    float e = __expf(-2.0f * a);
    float r = (1.0f - e) / (1.0f + e);
    return copysignf(r, v);
}

// ---------------- K0: W1 (H,C,HD) fp32 -> W1T[n][c] bf16, n = h*64+d ----------------
__global__ void k0_w1t(const float* __restrict__ W1, unsigned short* __restrict__ w1t) {
    int n = blockIdx.x;     // 256
    int c = threadIdx.x;    // 256
    int h = n >> 6, d = n & 63;
    float v = W1[(h * C_ + c) * HD_ + d];
    unsigned int u = __builtin_bit_cast(unsigned int, v);
    u = (u + 0x7fffu + ((u >> 16) & 1u)) >> 16;
    w1t[n * C_ + c] = (unsigned short)u;
}

// ---------------- K1 fused: scores (MFMA) + partial softmax + partial context ----------------
// grid 4096 (64 rows each), block 256 = 4 waves, wave w = head w.
// A: global -> regs (prefetch 1 ks ahead) -> bf16 pack -> LDS (double buffer, 1 barrier/iter).
// B: w1t direct global->reg, prefetched 1 ks ahead (128 KiB block-invariant, L1/L2-hot).
__global__ __launch_bounds__(256, 3)
void k1_fused(const float* __restrict__ x, const unsigned short* __restrict__ w1t,
              const float* __restrict__ b1, const float* __restrict__ w2,
              float* __restrict__ rawscore, float* __restrict__ ctxp,
              float* __restrict__ mS) {
    __shared__ __align__(16) unsigned short shA[2][64 * 40];  // 2 x (64 rows x 32k, stride 40)
    __shared__ float sS[4 * 64];                   // raw scores per head
    __shared__ __align__(16) float sP4[64 * 4];    // exp(s - m_loc), layout [t][h]

    const int tid  = threadIdx.x;
    const int lane = tid & 63;
    const int w    = tid >> 6;        // wave id == head id
    const int nl   = lane & 15;
    const int q    = lane >> 4;
    const int rowbase = blockIdx.x * 64;       // row = b*T + t
    const int b       = blockIdx.x >> 6;       // 64 blocks per batch
    const int tbase   = (blockIdx.x & 63) * 64;

    floatx4 acc[4][4];
    #pragma unroll
    for (int i = 0; i < 4; ++i)
        #pragma unroll
        for (int j = 0; j < 4; ++j)
            acc[i][j] = (floatx4){0.f, 0.f, 0.f, 0.f};

    const int arow = tid >> 2;          // 0..63
    const int acol = (tid & 3) * 8;     // 0,8,16,24
    const float* aptr = x + (long)(rowbase + arow) * C_ + acol;
    const unsigned short* bBase = w1t + (long)(w * 64 + nl) * C_ + q * 8;

    // prefetch chunk 0 into registers
    float4 fa0 = ((const float4*)aptr)[0];
    float4 fa1 = ((const float4*)aptr)[1];
    uint4 bF[4], bN[4];
    #pragma unroll
    for (int nb = 0; nb < 4; ++nb)
        bF[nb] = *(const uint4*)(bBase + nb * 16 * C_);

    for (int ks = 0; ks < 8; ++ks) {
        const int p = ks & 1;
        // pack+store staged A chunk (regs -> LDS)
        uint4 ua;
        ua.x = pack_bf16x2(fa0.x, fa0.y); ua.y = pack_bf16x2(fa0.z, fa0.w);
        ua.z = pack_bf16x2(fa1.x, fa1.y); ua.w = pack_bf16x2(fa1.z, fa1.w);
        *(uint4*)&shA[p][arow * 40 + acol] = ua;
        __syncthreads();
        // prefetch next chunk while this one computes
        if (ks < 7) {
            const float4* ap = (const float4*)(aptr + (ks + 1) * 32);
            fa0 = ap[0]; fa1 = ap[1];
            #pragma unroll
            for (int nb = 0; nb < 4; ++nb)
                bN[nb] = *(const uint4*)(bBase + nb * 16 * C_ + (ks + 1) * 32);
        }
        short8 aF[4];
        #pragma unroll
        for (int mb = 0; mb < 4; ++mb)
            aF[mb] = *(const short8*)&shA[p][(mb * 16 + nl) * 40 + q * 8];
        #pragma unroll
        for (int mb = 0; mb < 4; ++mb)
            #pragma unroll
            for (int nb = 0; nb < 4; ++nb)
                acc[mb][nb] = __builtin_amdgcn_mfma_f32_16x16x32_bf16(
                    aF[mb], __builtin_bit_cast(short8, bF[nb]), acc[mb][nb], 0, 0, 0);
        #pragma unroll
        for (int nb = 0; nb < 4; ++nb)
            bF[nb] = bN[nb];
    }

    // epilogue: s(t) = sum_d tanh(P + b1)*w2  (d = nb*16 + nl, t = mb*16 + q*4 + r)
    float b1v[4], w2v[4];
    #pragma unroll
    for (int nb = 0; nb < 4; ++nb) {
        int d = nb * 16 + nl;
        b1v[nb] = b1[w * HD_ + d];
        w2v[nb] = w2[w * HD_ + d];
    }
    #pragma unroll
    for (int mb = 0; mb < 4; ++mb) {
        float p[4];
        #pragma unroll
        for (int r = 0; r < 4; ++r) {
            float s = 0.f;
            #pragma unroll
            for (int nb = 0; nb < 4; ++nb)
                s += fast_tanh(acc[mb][nb][r] + b1v[nb]) * w2v[nb];
            p[r] = s;
        }
        #pragma unroll
        for (int m = 1; m < 16; m <<= 1)
            #pragma unroll
            for (int r = 0; r < 4; ++r)
                p[r] += __shfl_xor(p[r], m, 64);
        if (nl == 0) {
            #pragma unroll
            for (int r = 0; r < 4; ++r)
                sS[w * 64 + mb * 16 + q * 4 + r] = p[r];
        }
    }

    // phase 2: per-head local softmax partials over this block's 64 t values
    {
        float s = sS[w * 64 + lane];
        float m = s;
        #pragma unroll
        for (int off = 1; off < 64; off <<= 1)
            m = fmaxf(m, __shfl_xor(m, off, 64));
        float e = __expf(s - m);
        float Ss = e;
        #pragma unroll
        for (int off = 1; off < 64; off <<= 1)
            Ss += __shfl_xor(Ss, off, 64);
        sP4[lane * 4 + w] = e;                     // [t][h] for vectorized phase-3 read
        rawscore[((long)(b * H_ + w)) * T_ + tbase + lane] = s;
        if (lane == 0) {
            mS[((long)blockIdx.x * H_ + w) * 2 + 0] = m;
            mS[((long)blockIdx.x * H_ + w) * 2 + 1] = Ss;
        }
    }
    __syncthreads();

    // phase 3: partial contexts ctx_loc[h][c] = sum_t p[t][h] * x[t][c]  (x re-read, L2-hot)
    {
        float c0 = 0.f, c1 = 0.f, c2 = 0.f, c3 = 0.f;
        const float* xr = x + (long)rowbase * C_ + tid;
        const float4* pv4 = (const float4*)sP4;
        #pragma unroll 8
        for (int t = 0; t < 64; ++t) {
            float xv = xr[(long)t * C_];
            float4 pv = pv4[t];                    // one broadcast ds_read_b128
            c0 += pv.x * xv;
            c1 += pv.y * xv;
            c2 += pv.z * xv;
            c3 += pv.w * xv;
        }
        float* o = ctxp + (long)blockIdx.x * (H_ * C_) + tid;
        o[0]   = c0;
        o[256] = c1;
        o[512] = c2;
        o[768] = c3;
    }
}

// ---------------- K2: combine partials -> weights (in-place over raw scores) + multi ----------------
__global__ void k2_combine(const float* __restrict__ ctxp, const float* __restrict__ mS,
                           float* __restrict__ weights, float* __restrict__ multi) {
    __shared__ float sm[64], sSl[64], sc[64];
    int bh = blockIdx.x;              // b*H + h
    int b = bh >> 2, h = bh & 3;
    int tid = threadIdx.x;
    if (tid < 64) {
        long blk = (long)b * 64 + tid;
        sm[tid]  = mS[(blk * H_ + h) * 2 + 0];
        sSl[tid] = mS[(blk * H_ + h) * 2 + 1];
    }
    __syncthreads();
    float m = -INFINITY;
    #pragma unroll 8
    for (int j = 0; j < 64; ++j) m = fmaxf(m, sm[j]);
    if (tid < 64) sc[tid] = __expf(sm[tid] - m);
    __syncthreads();
    float S = 0.f;
    #pragma unroll 8
    for (int j = 0; j < 64; ++j) S += sSl[j] * sc[j];
    float invS = 1.0f / S;

    float acc = 0.f;
    #pragma unroll 4
    for (int j = 0; j < 64; ++j)
        acc += ctxp[((long)(b * 64 + j) * H_ + h) * C_ + tid] * sc[j];
    multi[(long)b * (H_ * C_) + h * C_ + tid] = acc * invS;

    float* wr = weights + (long)bh * T_;
    #pragma unroll
    for (int i = 0; i < 16; ++i) {
        int t = tid + i * 256;
        float sv = wr[t];                 // raw score written by k1_fused
        wr[t] = __expf(sv - m) * invS;
    }
}

// ---------------- K4: Wo projection + bias + LayerNorm ----------------
__global__ void k4_out(const float* __restrict__ multiG, const float* __restrict__ Wo,
                       const float* __restrict__ bo, const float* __restrict__ gamma,
                       const float* __restrict__ beta, float* __restrict__ out) {
    __shared__ float multi[1024];
    __shared__ float red[256];
    int b = blockIdx.x, tid = threadIdx.x;
    {
        const float4* src = (const float4*)(multiG + (long)b * 1024);
        float4* dst = (float4*)multi;
        dst[tid] = src[tid];   // 256 float4 = 1024 floats
    }
    __syncthreads();
    float a0 = 0.f, a1 = 0.f, a2 = 0.f, a3 = 0.f;
    const float4* wrow = (const float4*)(Wo + (long)tid * 1024);
    const float4* mv = (const float4*)multi;
    #pragma unroll 8
    for (int j4 = 0; j4 < 256; j4 += 4) {
        float4 w0 = wrow[j4],     m0 = mv[j4];
        float4 w1 = wrow[j4 + 1], m1 = mv[j4 + 1];
        float4 w2 = wrow[j4 + 2], m2 = mv[j4 + 2];
        float4 w3 = wrow[j4 + 3], m3 = mv[j4 + 3];
        a0 += m0.x * w0.x + m0.y * w0.y + m0.z * w0.z + m0.w * w0.w;
        a1 += m1.x * w1.x + m1.y * w1.y + m1.z * w1.z + m1.w * w1.w;
        a2 += m2.x * w2.x + m2.y * w2.y + m2.z * w2.z + m2.w * w2.w;
        a3 += m3.x * w3.x + m3.y * w3.y + m3.z * w3.z + m3.w * w3.w;
    }
    float acc = bo[tid] + ((a0 + a1) + (a2 + a3));
    red[tid] = acc; __syncthreads();
    for (int st = 128; st > 0; st >>= 1) {
        if (tid < st) red[tid] += red[tid + st];
        __syncthreads();
    }
    float mu = red[0] * (1.0f / 256.0f); __syncthreads();
    float dv = acc - mu;
    red[tid] = dv * dv; __syncthreads();
    for (int st = 128; st > 0; st >>= 1) {
        if (tid < st) red[tid] += red[tid + st];
        __syncthreads();
    }
    float var = red[0] * (1.0f / 256.0f);
    out[(long)b * C_ + tid] = dv * rsqrtf(var + EPS_) * gamma[tid] + beta[tid];
}

extern "C" void kernel_launch(void* const* d_in, const int* in_sizes, int n_in,
                              void* d_out, int out_size, void* d_ws, size_t ws_size,
                              hipStream_t stream) {
    const float* x     = (const float*)d_in[0];
    const float* W1    = (const float*)d_in[1];
    const float* b1    = (const float*)d_in[2];
    const float* w2    = (const float*)d_in[3];
    const float* Wo    = (const float*)d_in[4];
    const float* bo    = (const float*)d_in[5];
    const float* gamma = (const float*)d_in[6];
    const float* beta  = (const float*)d_in[7];

    float* out     = (float*)d_out;          // (B,C) = 16384 floats
    float* weights = out + B_ * C_;          // (B,H,T) = 1048576 floats (holds raw scores first)

    // workspace: ctxp 4096*4*256 fp32 (16 MiB) + mS 4096*4*2 + multi 64*1024 + w1t
    float* ctxp  = (float*)d_ws;
    float* mS    = ctxp + (long)4096 * H_ * C_;
    float* multi = mS + (long)4096 * H_ * 2;
    unsigned short* w1t = (unsigned short*)(multi + B_ * H_ * C_);

    k0_w1t    <<<256, 256, 0, stream>>>(W1, w1t);
    k1_fused  <<<4096, 256, 0, stream>>>(x, w1t, b1, w2, weights, ctxp, mS);
    k2_combine<<<256, 256, 0, stream>>>(ctxp, mS, weights, multi);
    k4_out    <<<64, 256, 0, stream>>>(multi, Wo, bo, gamma, beta, out);
}

// Round 5
// 475.287 us; speedup vs baseline: 1.2088x; 1.0217x over previous
//
#include <hip/hip_runtime.h>
#include <hip/hip_bf16.h>
#include <math.h>

#define B_ 64
#define T_ 4096
#define C_ 256
#define H_ 4
#define HD_ 64
#define EPS_ 1e-5f

typedef __attribute__((ext_vector_type(4))) float floatx4;
typedef __attribute__((ext_vector_type(8))) short short8;   // 8 bf16 = 4 VGPRs (MFMA A/B frag)

#if __has_builtin(__builtin_amdgcn_cvt_pk_bf16_f32)
typedef __attribute__((ext_vector_type(2))) __bf16 bf16x2_t;
__device__ __forceinline__ unsigned int pack_bf16x2(float a, float b) {
    bf16x2_t v = __builtin_amdgcn_cvt_pk_bf16_f32(a, b);
    return __builtin_bit_cast(unsigned int, v);
}
#else
__device__ __forceinline__ unsigned int pack_bf16x2(float a, float b) {
    unsigned int ua = __builtin_bit_cast(unsigned int, a);
    unsigned int ub = __builtin_bit_cast(unsigned int, b);
    ua = (ua + 0x7fffu + ((ua >> 16) & 1u)) >> 16;   // RNE
    ub = (ub + 0x7fffu + ((ub >> 16) & 1u)) >> 16;
    return ua | (ub << 16);
}
#endif

// tanh(x) = sign(x) * (1 - e) / (1 + e), e = exp(-2|x|)
__device__ __forceinline__ float fast_tanh(float v) {
    float a = fabsf(v);
    float e = __expf(-2.0f * a);
    float r = (1.0f - e) / (1.0f + e);
    return copysignf(r, v);
}

// ---------------- K0: W1 (H,C,HD) fp32 -> W1T[n][c] bf16, n = h*64+d ----------------
__global__ void k0_w1t(const float* __restrict__ W1, unsigned short* __restrict__ w1t) {
    int n = blockIdx.x;     // 256
    int c = threadIdx.x;    // 256
    int h = n >> 6, d = n & 63;
    float v = W1[(h * C_ + c) * HD_ + d];
    unsigned int u = __builtin_bit_cast(unsigned int, v);
    u = (u + 0x7fffu + ((u >> 16) & 1u)) >> 16;
    w1t[n * C_ + c] = (unsigned short)u;
}

// ---------------- K1 fused: scores (MFMA) + partial softmax + partial context ----------------
// grid 4096 (64 rows each), block 256 = 4 waves, wave w = head w.
// Full 64x256 bf16 A-tile staged to LDS once (ONE barrier); K-loop barrier-free.
// B (w1t, 128 KiB block-invariant, L2-hot) read direct to regs each K-step.
#define ASTRIDE 264   // bf16 elements per row (256 + 8 pad); 132 dwords, %32==4 -> 2-way only
__global__ __launch_bounds__(256, 4)
void k1_fused(const float* __restrict__ x, const unsigned short* __restrict__ w1t,
              const float* __restrict__ b1, const float* __restrict__ w2,
              float* __restrict__ rawscore, float* __restrict__ ctxp,
              float* __restrict__ mS) {
    __shared__ __align__(16) unsigned short shA[64 * ASTRIDE];  // 33 KiB, whole A tile
    __shared__ float sS[4 * 64];                   // raw scores per head
    __shared__ __align__(16) float sP4[64 * 4];    // exp(s - m_loc), layout [t][h]

    const int tid  = threadIdx.x;
    const int lane = tid & 63;
    const int w    = tid >> 6;        // wave id == head id
    const int nl   = lane & 15;
    const int q    = lane >> 4;
    const int rowbase = blockIdx.x * 64;       // row = b*T + t
    const int b       = blockIdx.x >> 6;       // 64 blocks per batch
    const int tbase   = (blockIdx.x & 63) * 64;

    // ---- stage full A tile: thread -> row tid>>2, col-group (tid&3)*8, 8 k-chunks ----
    const int arow = tid >> 2;          // 0..63
    const int acol = (tid & 3) * 8;     // 0,8,16,24 within each 32-chunk
    const float* aptr = x + (long)(rowbase + arow) * C_ + acol;
    #pragma unroll
    for (int kc = 0; kc < 8; ++kc) {
        const float4* ap = (const float4*)(aptr + kc * 32);
        float4 f0 = ap[0], f1 = ap[1];
        uint4 ua;
        ua.x = pack_bf16x2(f0.x, f0.y); ua.y = pack_bf16x2(f0.z, f0.w);
        ua.z = pack_bf16x2(f1.x, f1.y); ua.w = pack_bf16x2(f1.z, f1.w);
        *(uint4*)&shA[arow * ASTRIDE + kc * 32 + acol] = ua;
    }

    floatx4 acc[4][4];
    #pragma unroll
    for (int i = 0; i < 4; ++i)
        #pragma unroll
        for (int j = 0; j < 4; ++j)
            acc[i][j] = (floatx4){0.f, 0.f, 0.f, 0.f};

    const unsigned short* bBase = w1t + (long)(w * 64 + nl) * C_ + q * 8;
    __syncthreads();   // the ONLY K-side barrier

    // ---- barrier-free K-loop: 8 steps x 16 MFMA ----
    for (int ks = 0; ks < 8; ++ks) {
        uint4 bF[4];
        #pragma unroll
        for (int nb = 0; nb < 4; ++nb)
            bF[nb] = *(const uint4*)(bBase + nb * 16 * C_ + ks * 32);
        short8 aF[4];
        #pragma unroll
        for (int mb = 0; mb < 4; ++mb)
            aF[mb] = *(const short8*)&shA[(mb * 16 + nl) * ASTRIDE + ks * 32 + q * 8];
        #pragma unroll
        for (int mb = 0; mb < 4; ++mb)
            #pragma unroll
            for (int nb = 0; nb < 4; ++nb)
                acc[mb][nb] = __builtin_amdgcn_mfma_f32_16x16x32_bf16(
                    aF[mb], __builtin_bit_cast(short8, bF[nb]), acc[mb][nb], 0, 0, 0);
    }

    // ---- epilogue: s(t) = sum_d tanh(P + b1)*w2  (d = nb*16 + nl, t = mb*16 + q*4 + r) ----
    float b1v[4], w2v[4];
    #pragma unroll
    for (int nb = 0; nb < 4; ++nb) {
        int d = nb * 16 + nl;
        b1v[nb] = b1[w * HD_ + d];
        w2v[nb] = w2[w * HD_ + d];
    }
    #pragma unroll
    for (int mb = 0; mb < 4; ++mb) {
        float p[4];
        #pragma unroll
        for (int r = 0; r < 4; ++r) {
            float s = 0.f;
            #pragma unroll
            for (int nb = 0; nb < 4; ++nb)
                s += fast_tanh(acc[mb][nb][r] + b1v[nb]) * w2v[nb];
            p[r] = s;
        }
        #pragma unroll
        for (int m = 1; m < 16; m <<= 1)
            #pragma unroll
            for (int r = 0; r < 4; ++r)
                p[r] += __shfl_xor(p[r], m, 64);
        if (nl == 0) {
            #pragma unroll
            for (int r = 0; r < 4; ++r)
                sS[w * 64 + mb * 16 + q * 4 + r] = p[r];
        }
    }

    // ---- phase 2: per-head local softmax partials over this block's 64 t values ----
    {
        float s = sS[w * 64 + lane];
        float m = s;
        #pragma unroll
        for (int off = 1; off < 64; off <<= 1)
            m = fmaxf(m, __shfl_xor(m, off, 64));
        float e = __expf(s - m);
        float Ss = e;
        #pragma unroll
        for (int off = 1; off < 64; off <<= 1)
            Ss += __shfl_xor(Ss, off, 64);
        sP4[lane * 4 + w] = e;                     // [t][h] for vectorized phase-3 read
        rawscore[((long)(b * H_ + w)) * T_ + tbase + lane] = s;
        if (lane == 0) {
            mS[((long)blockIdx.x * H_ + w) * 2 + 0] = m;
            mS[((long)blockIdx.x * H_ + w) * 2 + 1] = Ss;
        }
    }
    __syncthreads();

    // ---- phase 3: partial contexts ctx_loc[h][c] = sum_t p[t][h] * x[t][c] (x re-read, L2-hot) ----
    {
        float c0 = 0.f, c1 = 0.f, c2 = 0.f, c3 = 0.f;
        const float* xr = x + (long)rowbase * C_ + tid;
        const float4* pv4 = (const float4*)sP4;
        #pragma unroll 8
        for (int t = 0; t < 64; ++t) {
            float xv = xr[(long)t * C_];
            float4 pv = pv4[t];                    // one broadcast ds_read_b128
            c0 += pv.x * xv;
            c1 += pv.y * xv;
            c2 += pv.z * xv;
            c3 += pv.w * xv;
        }
        float* o = ctxp + (long)blockIdx.x * (H_ * C_) + tid;
        o[0]   = c0;
        o[256] = c1;
        o[512] = c2;
        o[768] = c3;
    }
}

// ---------------- K2: combine partials -> weights (in-place over raw scores) + multi ----------------
__global__ void k2_combine(const float* __restrict__ ctxp, const float* __restrict__ mS,
                           float* __restrict__ weights, float* __restrict__ multi) {
    __shared__ float sm[64], sSl[64], sc[64];
    int bh = blockIdx.x;              // b*H + h
    int b = bh >> 2, h = bh & 3;
    int tid = threadIdx.x;
    if (tid < 64) {
        long blk = (long)b * 64 + tid;
        sm[tid]  = mS[(blk * H_ + h) * 2 + 0];
        sSl[tid] = mS[(blk * H_ + h) * 2 + 1];
    }
    __syncthreads();
    float m = -INFINITY;
    #pragma unroll 8
    for (int j = 0; j < 64; ++j) m = fmaxf(m, sm[j]);
    if (tid < 64) sc[tid] = __expf(sm[tid] - m);
    __syncthreads();
    float S = 0.f;
    #pragma unroll 8
    for (int j = 0; j < 64; ++j) S += sSl[j] * sc[j];
    float invS = 1.0f / S;

    float acc = 0.f;
    #pragma unroll 4
    for (int j = 0; j < 64; ++j)
        acc += ctxp[((long)(b * 64 + j) * H_ + h) * C_ + tid] * sc[j];
    multi[(long)b * (H_ * C_) + h * C_ + tid] = acc * invS;

    float* wr = weights + (long)bh * T_;
    #pragma unroll
    for (int i = 0; i < 16; ++i) {
        int t = tid + i * 256;
        float sv = wr[t];                 // raw score written by k1_fused
        wr[t] = __expf(sv - m) * invS;
    }
}

// ---------------- K4: Wo projection + bias + LayerNorm ----------------
__global__ void k4_out(const float* __restrict__ multiG, const float* __restrict__ Wo,
                       const float* __restrict__ bo, const float* __restrict__ gamma,
                       const float* __restrict__ beta, float* __restrict__ out) {
    __shared__ float multi[1024];
    __shared__ float red[256];
    int b = blockIdx.x, tid = threadIdx.x;
    {
        const float4* src = (const float4*)(multiG + (long)b * 1024);
        float4* dst = (float4*)multi;
        dst[tid] = src[tid];   // 256 float4 = 1024 floats
    }
    __syncthreads();
    float a0 = 0.f, a1 = 0.f, a2 = 0.f, a3 = 0.f;
    const float4* wrow = (const float4*)(Wo + (long)tid * 1024);
    const float4* mv = (const float4*)multi;
    #pragma unroll 8
    for (int j4 = 0; j4 < 256; j4 += 4) {
        float4 w0 = wrow[j4],     m0 = mv[j4];
        float4 w1 = wrow[j4 + 1], m1 = mv[j4 + 1];
        float4 w2 = wrow[j4 + 2], m2 = mv[j4 + 2];
        float4 w3 = wrow[j4 + 3], m3 = mv[j4 + 3];
        a0 += m0.x * w0.x + m0.y * w0.y + m0.z * w0.z + m0.w * w0.w;
        a1 += m1.x * w1.x + m1.y * w1.y + m1.z * w1.z + m1.w * w1.w;
        a2 += m2.x * w2.x + m2.y * w2.y + m2.z * w2.z + m2.w * w2.w;
        a3 += m3.x * w3.x + m3.y * w3.y + m3.z * w3.z + m3.w * w3.w;
    }
    float acc = bo[tid] + ((a0 + a1) + (a2 + a3));
    red[tid] = acc; __syncthreads();
    for (int st = 128; st > 0; st >>= 1) {
        if (tid < st) red[tid] += red[tid + st];
        __syncthreads();
    }
    float mu = red[0] * (1.0f / 256.0f); __syncthreads();
    float dv = acc - mu;
    red[tid] = dv * dv; __syncthreads();
    for (int st = 128; st > 0; st >>= 1) {
        if (tid < st) red[tid] += red[tid + st];
        __syncthreads();
    }
    float var = red[0] * (1.0f / 256.0f);
    out[(long)b * C_ + tid] = dv * rsqrtf(var + EPS_) * gamma[tid] + beta[tid];
}

extern "C" void kernel_launch(void* const* d_in, const int* in_sizes, int n_in,
                              void* d_out, int out_size, void* d_ws, size_t ws_size,
                              hipStream_t stream) {
    const float* x     = (const float*)d_in[0];
    const float* W1    = (const float*)d_in[1];
    const float* b1    = (const float*)d_in[2];
    const float* w2    = (const float*)d_in[3];
    const float* Wo    = (const float*)d_in[4];
    const float* bo    = (const float*)d_in[5];
    const float* gamma = (const float*)d_in[6];
    const float* beta  = (const float*)d_in[7];

    float* out     = (float*)d_out;          // (B,C) = 16384 floats
    float* weights = out + B_ * C_;          // (B,H,T) = 1048576 floats (holds raw scores first)

    // workspace: ctxp 4096*4*256 fp32 (16 MiB) + mS 4096*4*2 + multi 64*1024 + w1t
    float* ctxp  = (float*)d_ws;
    float* mS    = ctxp + (long)4096 * H_ * C_;
    float* multi = mS + (long)4096 * H_ * 2;
    unsigned short* w1t = (unsigned short*)(multi + B_ * H_ * C_);

    k0_w1t    <<<256, 256, 0, stream>>>(W1, w1t);
    k1_fused  <<<4096, 256, 0, stream>>>(x, w1t, b1, w2, weights, ctxp, mS);
    k2_combine<<<256, 256, 0, stream>>>(ctxp, mS, weights, multi);
    k4_out    <<<64, 256, 0, stream>>>(multi, Wo, bo, gamma, beta, out);
}